// Round 9
// baseline (476.834 us; speedup 1.0000x reference)
//
#include <hip/hip_runtime.h>
#include <hip/hip_bf16.h>

typedef __attribute__((ext_vector_type(8))) short short8;
typedef __attribute__((ext_vector_type(4))) float f32x4;

#define NOUT  16777216
#define DELTA 0.065f
#define NINF  -3.4e38f

// ---------------------------------------------------------------------------
// Kernel 1: normalize prototypes, write pnN f32 [p][k] and bf16 copy pnBF.
// ---------------------------------------------------------------------------
__global__ __launch_bounds__(256) void proto_prep(
    const float* __restrict__ proto, float* __restrict__ pnN,
    ushort* __restrict__ pnBF) {
  int p = blockIdx.x;       // 0..511
  int c = threadIdx.x;      // 0..255
  float v = proto[p * 256 + c];
  float s = v * v;
  #pragma unroll
  for (int off = 32; off > 0; off >>= 1) s += __shfl_down(s, off);
  __shared__ float red[4];
  int lane = c & 63, wid = c >> 6;
  if (lane == 0) red[wid] = s;
  __syncthreads();
  float tot = red[0] + red[1] + red[2] + red[3];
  float nrm = fmaxf(sqrtf(tot), 1e-12f);
  float q = v / nrm;
  pnN[p * 256 + c] = q;
  __hip_bfloat16 h = __float2bfloat16(q);
  pnBF[p * 256 + c] = *reinterpret_cast<ushort*>(&h);
}

// exact fp32 dot over 256 k for one (pos, proto); wave-collective tree reduce.
__device__ __forceinline__ float dot256(const float* __restrict__ xc,
                                        const float* __restrict__ pn, int l) {
  f32x4 pv = *reinterpret_cast<const f32x4*>(pn + (l << 2));
  float s = 0.f;
  #pragma unroll
  for (int j = 0; j < 4; ++j)
    s = fmaf(xc[(size_t)(((l << 2) + j)) << 10], pv[j], s);
  #pragma unroll
  for (int d = 1; d < 64; d <<= 1) s += __shfl_xor(s, d);
  return s;
}

// exact fp32 argmax over ALL 512 protos for one pos (rare 3-way path).
__device__ __forceinline__ int full512(const float* __restrict__ xc,
                                       const float* __restrict__ pnN, int l) {
  float a[8];
  #pragma unroll
  for (int pp = 0; pp < 8; ++pp) a[pp] = 0.f;
  #pragma unroll 1
  for (int k4 = 0; k4 < 64; ++k4) {
    float xv[4];
    #pragma unroll
    for (int j = 0; j < 4; ++j) xv[j] = xc[(size_t)(((k4 << 2) + j)) << 10];
    #pragma unroll
    for (int pp = 0; pp < 8; ++pp) {
      f32x4 pv = *reinterpret_cast<const f32x4*>(
          pnN + ((((l << 3) + pp)) << 8) + (k4 << 2));
      #pragma unroll
      for (int j = 0; j < 4; ++j) a[pp] = fmaf(xv[j], pv[j], a[pp]);
    }
  }
  float bs = NINF; int bp = 0;
  #pragma unroll
  for (int pp = 0; pp < 8; ++pp) {
    int p = (l << 3) + pp;
    if (a[pp] > bs) { bs = a[pp]; bp = p; }   // ascending p: > keeps smallest
  }
  #pragma unroll
  for (int d = 1; d < 64; d <<= 1) {
    float os = __shfl_xor(bs, d); int op = __shfl_xor(bp, d);
    bool take = (os > bs) || (os == bs && op < bp);
    bs = take ? os : bs; bp = take ? op : bp;
  }
  return bp;
}

// ---------------------------------------------------------------------------
// Kernel 2: wave-independent (NO LDS, NO barriers). Each wave owns 32 pos:
//  - x tile (32 pos x 256 k) loaded straight from global into bf16 B-frags
//    (64 VGPRs); A = pnBF fragments streamed from L2 (validated pattern).
//  - D[proto][pos]; streaming top-3 (m1,i1,m2,i2,m3) per pos.
//  - m1-m2>=DELTA -> i1; else exact fp32 pair rescore; m1-m3<DELTA -> full512.
//  - fused idx write + recon gather (proto rows L2-resident).
// ---------------------------------------------------------------------------
__global__ __launch_bounds__(256, 4) void match_kernel(
    const float* __restrict__ x, const float* __restrict__ proto,
    const float* __restrict__ pnN, const ushort* __restrict__ pnBF,
    float* __restrict__ out) {
  const int t = threadIdx.x;
  const int l = t & 63;
  const int wave = (blockIdx.x << 2) + (t >> 6);
  const int pos0 = wave << 5;
  const int b = pos0 >> 10, hw0 = pos0 & 1023;
  const int lg = l >> 4, c16 = l & 15;

  const float* xg = x + ((size_t)b << 18) + hw0;

  // ---- x -> bf16 B-fragments, direct from global (coalesced 64B lines) ----
  short8 B[2][8];
  #pragma unroll
  for (int n = 0; n < 2; ++n)
    #pragma unroll
    for (int kk = 0; kk < 8; ++kk) {
      short8 pk;
      #pragma unroll
      for (int j = 0; j < 8; ++j) {
        float f = xg[(size_t)(((kk << 5) + (lg << 3) + j)) << 10 |
                     (unsigned)((n << 4) + c16)];
        __hip_bfloat16 h = __float2bfloat16(f);
        pk[j] = *reinterpret_cast<short*>(&h);
      }
      B[n][kk] = pk;
    }

  // ---- main loop: 32 proto-tiles x 8 k-steps, streaming top-3 tracking ----
  float m1[2] = {NINF, NINF}, m2[2] = {NINF, NINF}, m3[2] = {NINF, NINF};
  int i1[2] = {0, 0}, i2[2] = {0, 0};

  #pragma unroll 1
  for (int pt = 0; pt < 32; ++pt) {
    f32x4 acc0 = {0.f, 0.f, 0.f, 0.f}, acc1 = {0.f, 0.f, 0.f, 0.f};
    #pragma unroll
    for (int kk = 0; kk < 8; ++kk) {
      const short8 A = *reinterpret_cast<const short8*>(
          pnBF + (((pt << 4) + c16) << 8) + (kk << 5) + (lg << 3));
      acc0 = __builtin_amdgcn_mfma_f32_16x16x32_bf16(A, B[0][kk], acc0, 0, 0, 0);
      acc1 = __builtin_amdgcn_mfma_f32_16x16x32_bf16(A, B[1][kk], acc1, 0, 0, 0);
    }
    int pbase = (pt << 4) + (lg << 2);
    #pragma unroll
    for (int r = 0; r < 4; ++r) {
      {
        float v = acc0[r]; int p = pbase + r;
        bool g1 = v > m1[0], g2 = v > m2[0], g3 = v > m3[0];
        m3[0] = g2 ? m2[0] : (g3 ? v : m3[0]);
        m2[0] = g1 ? m1[0] : (g2 ? v : m2[0]);
        i2[0] = g1 ? i1[0] : (g2 ? p : i2[0]);
        m1[0] = g1 ? v : m1[0];
        i1[0] = g1 ? p : i1[0];
      }
      {
        float v = acc1[r]; int p = pbase + r;
        bool g1 = v > m1[1], g2 = v > m2[1], g3 = v > m3[1];
        m3[1] = g2 ? m2[1] : (g3 ? v : m3[1]);
        m2[1] = g1 ? m1[1] : (g2 ? v : m2[1]);
        i2[1] = g1 ? i1[1] : (g2 ? p : i2[1]);
        m1[1] = g1 ? v : m1[1];
        i1[1] = g1 ? p : i1[1];
      }
    }
  }

  // ---- cross-lane merge (groups lg=0..3 partition protos) per pos-tile ----
  #pragma unroll
  for (int n = 0; n < 2; ++n) {
    #pragma unroll
    for (int d = 16; d <= 32; d <<= 1) {
      float bm1 = __shfl_xor(m1[n], d), bm2 = __shfl_xor(m2[n], d),
            bm3 = __shfl_xor(m3[n], d);
      int bi1 = __shfl_xor(i1[n], d), bi2 = __shfl_xor(i2[n], d);
      bool aF = (m1[n] > bm1) || (m1[n] == bm1 && i1[n] < bi1);
      float a1 = aF ? m1[n] : bm1, a2 = aF ? m2[n] : bm2, a3 = aF ? m3[n] : bm3;
      int ai1 = aF ? i1[n] : bi1, ai2 = aF ? i2[n] : bi2;
      float o1 = aF ? bm1 : m1[n], o2 = aF ? bm2 : m2[n];
      int oi1 = aF ? bi1 : i1[n];
      bool c2 = (a2 > o1) || (a2 == o1 && ai2 < oi1);
      m1[n] = a1; i1[n] = ai1;
      m2[n] = c2 ? a2 : o1; i2[n] = c2 ? ai2 : oi1;
      m3[n] = fmaxf(fmaxf(a3, o2), c2 ? o1 : a2);
    }
  }

  // ---- resolve ambiguous positions with exact fp32 ----
  int idxn[2];
  #pragma unroll 1
  for (int n = 0; n < 2; ++n) {
    idxn[n] = i1[n];
    bool need2 = (m1[n] - m2[n]) < DELTA;
    bool need3 = (m1[n] - m3[n]) < DELTA;
    unsigned msk = (unsigned)(__ballot(need2) & 0xFFFFull);
    while (msk) {
      int pr = __ffs(msk) - 1; msk &= msk - 1;
      int I1 = __shfl(i1[n], pr), I2 = __shfl(i2[n], pr);
      int isC = __shfl((int)need3, pr);
      const float* xc = x + ((size_t)b << 18) + (hw0 + (n << 4) + pr);
      int win;
      if (!isC) {
        float s1 = dot256(xc, pnN + (I1 << 8), l);
        float s2 = dot256(xc, pnN + (I2 << 8), l);
        win = (s2 > s1 || (s2 == s1 && I2 < I1)) ? I2 : I1;
      } else {
        win = full512(xc, pnN, l);
      }
      if (c16 == pr) idxn[n] = win;
    }
  }

  // ---- per-lane idx for pos l&31, write idx output ----
  int v0 = __shfl(idxn[0], c16), v1 = __shfl(idxn[1], c16);
  int pidx = ((l >> 4) & 1) ? v1 : v0;
  if (l < 32) out[(size_t)NOUT + pos0 + l] = (float)pidx;

  // ---- fused recon gather: out[b][c][pos] = proto[pidx][c] ----
  const float4* proto4 = reinterpret_cast<const float4*>(proto);
  float* ob = out + ((size_t)b << 18) + hw0 + (l & 31);
  #pragma unroll 1
  for (int it = 0; it < 32; ++it) {
    int c4 = (it << 1) + (l >> 5);        // 0..63
    float4 v = proto4[(pidx << 6) + c4];
    #pragma unroll
    for (int j = 0; j < 4; ++j)
      ob[(size_t)(((c4 << 2) + j)) << 10] = (&v.x)[j];
  }
}

extern "C" void kernel_launch(void* const* d_in, const int* in_sizes, int n_in,
                              void* d_out, int out_size, void* d_ws, size_t ws_size,
                              hipStream_t stream) {
  const float* x = (const float*)d_in[0];        // (64, 256, 32, 32) f32
  const float* proto = (const float*)d_in[1];    // (512, 256) f32
  float* out = (float*)d_out;                    // 16777216 recon + 65536 idx
  float* pnN = (float*)d_ws;                     // 512*256 f32 = 512 KB
  ushort* pnBF = (ushort*)((char*)d_ws + 512 * 256 * sizeof(float)); // 256 KB

  proto_prep<<<512, 256, 0, stream>>>(proto, pnN, pnBF);
  match_kernel<<<512, 256, 0, stream>>>(x, proto, pnN, pnBF, out);
}

// Round 10
// 468.414 us; speedup vs baseline: 1.0180x; 1.0180x over previous
//
#include <hip/hip_runtime.h>
#include <hip/hip_bf16.h>

typedef __attribute__((ext_vector_type(8))) short short8;
typedef __attribute__((ext_vector_type(4))) float f32x4;

#define NOUT  16777216
#define DELTA 0.065f
#define NINF  -3.4e38f

// ---------------------------------------------------------------------------
// Kernel 1: normalize prototypes, write pnN f32 [p][k] and bf16 copy pnBF.
// ---------------------------------------------------------------------------
__global__ __launch_bounds__(256) void proto_prep(
    const float* __restrict__ proto, float* __restrict__ pnN,
    ushort* __restrict__ pnBF) {
  int p = blockIdx.x;       // 0..511
  int c = threadIdx.x;      // 0..255
  float v = proto[p * 256 + c];
  float s = v * v;
  #pragma unroll
  for (int off = 32; off > 0; off >>= 1) s += __shfl_down(s, off);
  __shared__ float red[4];
  int lane = c & 63, wid = c >> 6;
  if (lane == 0) red[wid] = s;
  __syncthreads();
  float tot = red[0] + red[1] + red[2] + red[3];
  float nrm = fmaxf(sqrtf(tot), 1e-12f);
  float q = v / nrm;
  pnN[p * 256 + c] = q;
  __hip_bfloat16 h = __float2bfloat16(q);
  pnBF[p * 256 + c] = *reinterpret_cast<ushort*>(&h);
}

// exact fp32 dot over 256 k for one (pos, proto); wave-collective tree reduce.
__device__ __forceinline__ float dot256(const float* __restrict__ xc,
                                        const float* __restrict__ pn, int l) {
  f32x4 pv = *reinterpret_cast<const f32x4*>(pn + (l << 2));
  float s = 0.f;
  #pragma unroll
  for (int j = 0; j < 4; ++j)
    s = fmaf(xc[(size_t)(((l << 2) + j)) << 10], pv[j], s);
  #pragma unroll
  for (int d = 1; d < 64; d <<= 1) s += __shfl_xor(s, d);
  return s;
}

// exact fp32 argmax over ALL 512 protos for one pos (rare 3-way path).
__device__ __forceinline__ int full512(const float* __restrict__ xc,
                                       const float* __restrict__ pnN, int l) {
  float a[8];
  #pragma unroll
  for (int pp = 0; pp < 8; ++pp) a[pp] = 0.f;
  #pragma unroll 1
  for (int k4 = 0; k4 < 64; ++k4) {
    float xv[4];
    #pragma unroll
    for (int j = 0; j < 4; ++j) xv[j] = xc[(size_t)(((k4 << 2) + j)) << 10];
    #pragma unroll
    for (int pp = 0; pp < 8; ++pp) {
      f32x4 pv = *reinterpret_cast<const f32x4*>(
          pnN + ((((l << 3) + pp)) << 8) + (k4 << 2));
      #pragma unroll
      for (int j = 0; j < 4; ++j) a[pp] = fmaf(xv[j], pv[j], a[pp]);
    }
  }
  float bs = NINF; int bp = 0;
  #pragma unroll
  for (int pp = 0; pp < 8; ++pp) {
    int p = (l << 3) + pp;
    if (a[pp] > bs) { bs = a[pp]; bp = p; }
  }
  #pragma unroll
  for (int d = 1; d < 64; d <<= 1) {
    float os = __shfl_xor(bs, d); int op = __shfl_xor(bp, d);
    bool take = (os > bs) || (os == bs && op < bp);
    bs = take ? os : bs; bp = take ? op : bp;
  }
  return bp;
}

// ---------------------------------------------------------------------------
// Kernel 2: block = 64 pos, 8 waves = 2 pos-groups (32 pos) x 4 proto-groups
// (128 protos). r9's validated math (direct-global B-frags, operand-swap
// MFMA, streaming top-3, DELTA merge, dot256/full512 resolve) with 4x more
// waves and cross-wg LDS merge. Tail gather = r4's validated loop.
// ---------------------------------------------------------------------------
__global__ __launch_bounds__(512, 2) void match_kernel(
    const float* __restrict__ x, const float* __restrict__ proto,
    const float* __restrict__ pnN, const ushort* __restrict__ pnBF,
    float* __restrict__ out) {
  __shared__ float m1s[2][4][32], m2s[2][4][32], m3s[2][4][32];
  __shared__ int   i1s[2][4][32], i2s[2][4][32];
  __shared__ int   idxl[64];

  const int t = threadIdx.x;
  const int l = t & 63, w = t >> 6;
  const int pg = w >> 2, wg = w & 3;
  const int lg = l >> 4, c16 = l & 15;
  const int n0 = blockIdx.x << 6;
  const int b = n0 >> 10, hw0 = n0 & 1023;
  const float* xg = x + ((size_t)b << 18) + hw0 + (pg << 5);

  // ---- x -> bf16 B-fragments for this wave's 32 positions (r9 pattern) ----
  short8 B[2][8];
  #pragma unroll
  for (int n = 0; n < 2; ++n)
    #pragma unroll
    for (int kk = 0; kk < 8; ++kk) {
      short8 pk;
      #pragma unroll
      for (int j = 0; j < 8; ++j) {
        float f = xg[(size_t)(((kk << 5) + (lg << 3) + j)) << 10 |
                     (unsigned)((n << 4) + c16)];
        __hip_bfloat16 h = __float2bfloat16(f);
        pk[j] = *reinterpret_cast<short*>(&h);
      }
      B[n][kk] = pk;
    }

  // ---- 8 proto-tiles (this wg's 128 protos), streaming top-3 ----
  float m1[2] = {NINF, NINF}, m2[2] = {NINF, NINF}, m3[2] = {NINF, NINF};
  int i1[2] = {0, 0}, i2[2] = {0, 0};

  #pragma unroll 1
  for (int pti = 0; pti < 8; ++pti) {
    int pt = (wg << 3) + pti;
    f32x4 acc0 = {0.f, 0.f, 0.f, 0.f}, acc1 = {0.f, 0.f, 0.f, 0.f};
    #pragma unroll
    for (int kk = 0; kk < 8; ++kk) {
      const short8 A = *reinterpret_cast<const short8*>(
          pnBF + (((pt << 4) + c16) << 8) + (kk << 5) + (lg << 3));
      acc0 = __builtin_amdgcn_mfma_f32_16x16x32_bf16(A, B[0][kk], acc0, 0, 0, 0);
      acc1 = __builtin_amdgcn_mfma_f32_16x16x32_bf16(A, B[1][kk], acc1, 0, 0, 0);
    }
    int pbase = (pt << 4) + (lg << 2);
    #pragma unroll
    for (int r = 0; r < 4; ++r) {
      {
        float v = acc0[r]; int p = pbase + r;
        bool g1 = v > m1[0], g2 = v > m2[0], g3 = v > m3[0];
        m3[0] = g2 ? m2[0] : (g3 ? v : m3[0]);
        m2[0] = g1 ? m1[0] : (g2 ? v : m2[0]);
        i2[0] = g1 ? i1[0] : (g2 ? p : i2[0]);
        m1[0] = g1 ? v : m1[0];
        i1[0] = g1 ? p : i1[0];
      }
      {
        float v = acc1[r]; int p = pbase + r;
        bool g1 = v > m1[1], g2 = v > m2[1], g3 = v > m3[1];
        m3[1] = g2 ? m2[1] : (g3 ? v : m3[1]);
        m2[1] = g1 ? m1[1] : (g2 ? v : m2[1]);
        i2[1] = g1 ? i1[1] : (g2 ? p : i2[1]);
        m1[1] = g1 ? v : m1[1];
        i1[1] = g1 ? p : i1[1];
      }
    }
  }

  // ---- cross-lane merge within wave (r9 validated) ----
  #pragma unroll
  for (int n = 0; n < 2; ++n) {
    #pragma unroll
    for (int d = 16; d <= 32; d <<= 1) {
      float bm1 = __shfl_xor(m1[n], d), bm2 = __shfl_xor(m2[n], d),
            bm3 = __shfl_xor(m3[n], d);
      int bi1 = __shfl_xor(i1[n], d), bi2 = __shfl_xor(i2[n], d);
      bool aF = (m1[n] > bm1) || (m1[n] == bm1 && i1[n] < bi1);
      float a1 = aF ? m1[n] : bm1, a2 = aF ? m2[n] : bm2, a3 = aF ? m3[n] : bm3;
      int ai1 = aF ? i1[n] : bi1, ai2 = aF ? i2[n] : bi2;
      float o1 = aF ? bm1 : m1[n], o2 = aF ? bm2 : m2[n];
      int oi1 = aF ? bi1 : i1[n];
      bool c2 = (a2 > o1) || (a2 == o1 && ai2 < oi1);
      m1[n] = a1; i1[n] = ai1;
      m2[n] = c2 ? a2 : o1; i2[n] = c2 ? ai2 : oi1;
      m3[n] = fmaxf(fmaxf(a3, o2), c2 ? o1 : a2);
    }
  }

  // ---- publish per-(pg,wg) top-3 tuples (lane l<32 holds pos l state) ----
  if (l < 32) {
    int n = l >> 4;
    m1s[pg][wg][l] = m1[n]; m2s[pg][wg][l] = m2[n]; m3s[pg][wg][l] = m3[n];
    i1s[pg][wg][l] = i1[n]; i2s[pg][wg][l] = i2[n];
  }
  __syncthreads();

  // ---- every wave merges its pg's 4 tuples (pos = l&31) ----
  int ap31 = l & 31;
  float M1 = m1s[pg][0][ap31], M2 = m2s[pg][0][ap31], M3 = m3s[pg][0][ap31];
  int I1 = i1s[pg][0][ap31], I2 = i2s[pg][0][ap31];
  #pragma unroll
  for (int q = 1; q < 4; ++q) {
    float o1 = m1s[pg][q][ap31], o2 = m2s[pg][q][ap31], o3 = m3s[pg][q][ap31];
    int oi1 = i1s[pg][q][ap31], oi2 = i2s[pg][q][ap31];
    bool aF = (M1 > o1) || (M1 == o1 && I1 < oi1);
    float a1 = aF ? M1 : o1, a2 = aF ? M2 : o2, a3 = aF ? M3 : o3;
    int ai1 = aF ? I1 : oi1, ai2 = aF ? I2 : oi2;
    float b1 = aF ? o1 : M1, b2 = aF ? o2 : M2;
    int bi1 = aF ? oi1 : I1;
    bool c2 = (a2 > b1) || (a2 == b1 && ai2 < bi1);
    M1 = a1; I1 = ai1;
    M2 = c2 ? a2 : b1; I2 = c2 ? ai2 : bi1;
    M3 = fmaxf(fmaxf(a3, b2), c2 ? b1 : a2);
  }

  bool need2 = (l < 32) && ((M1 - M2) < DELTA);
  bool need3 = (M1 - M3) < DELTA;
  unsigned long long bal = __ballot(need2);

  // non-ambiguous defaults written once (wg 0)
  if (wg == 0 && l < 32 && !need2) idxl[(pg << 5) + l] = I1;

  // ambiguous positions: every 4th set bit handled by this wg's wave
  unsigned long long msk = bal;
  int rank = 0;
  while (msk) {
    int ap = __ffsll(msk) - 1; msk &= msk - 1;
    if ((rank++ & 3) != wg) continue;
    int c1 = __shfl(I1, ap), cc2 = __shfl(I2, ap);
    int isC = __shfl((int)need3, ap);
    const float* xc = x + ((size_t)b << 18) + (hw0 + (pg << 5) + ap);
    int win;
    if (!isC) {
      float s1 = dot256(xc, pnN + (c1 << 8), l);
      float s2 = dot256(xc, pnN + (cc2 << 8), l);
      win = (s2 > s1 || (s2 == s1 && cc2 < c1)) ? cc2 : c1;
    } else {
      win = full512(xc, pnN, l);
    }
    if (l == 0) idxl[(pg << 5) + ap] = win;
  }
  __syncthreads();

  // ---- idx output ----
  if (t < 64) out[(size_t)NOUT + n0 + t] = (float)idxl[t];

  // ---- recon gather (r4 validated): out[b][c][hw0+pos] = proto[idx][c] ----
  float* rb = out + ((size_t)b << 18) + hw0;
  #pragma unroll 1
  for (int it = 0; it < 32; ++it) {
    int lin = (it << 9) + t;
    int c = lin >> 6, pos = lin & 63;
    rb[((size_t)c << 10) + pos] = proto[(idxl[pos] << 8) + c];
  }
}

extern "C" void kernel_launch(void* const* d_in, const int* in_sizes, int n_in,
                              void* d_out, int out_size, void* d_ws, size_t ws_size,
                              hipStream_t stream) {
  const float* x = (const float*)d_in[0];        // (64, 256, 32, 32) f32
  const float* proto = (const float*)d_in[1];    // (512, 256) f32
  float* out = (float*)d_out;                    // 16777216 recon + 65536 idx
  float* pnN = (float*)d_ws;                     // 512*256 f32 = 512 KB
  ushort* pnBF = (ushort*)((char*)d_ws + 512 * 256 * sizeof(float)); // 256 KB

  proto_prep<<<512, 256, 0, stream>>>(proto, pnN, pnBF);
  match_kernel<<<1024, 512, 0, stream>>>(x, proto, pnN, pnBF, out);
}

// Round 11
// 449.902 us; speedup vs baseline: 1.0599x; 1.0411x over previous
//
#include <hip/hip_runtime.h>
#include <hip/hip_bf16.h>

typedef __attribute__((ext_vector_type(8))) short short8;
typedef __attribute__((ext_vector_type(4))) float f32x4;

#define NOUT  16777216
#define DELTA 0.065f
#define NINF  -3.4e38f

// ---------------------------------------------------------------------------
// Kernel 1: normalize prototypes, write pnN f32 [p][k] and bf16 copy pnBF.
// ---------------------------------------------------------------------------
__global__ __launch_bounds__(256) void proto_prep(
    const float* __restrict__ proto, float* __restrict__ pnN,
    ushort* __restrict__ pnBF) {
  int p = blockIdx.x;       // 0..511
  int c = threadIdx.x;      // 0..255
  float v = proto[p * 256 + c];
  float s = v * v;
  #pragma unroll
  for (int off = 32; off > 0; off >>= 1) s += __shfl_down(s, off);
  __shared__ float red[4];
  int lane = c & 63, wid = c >> 6;
  if (lane == 0) red[wid] = s;
  __syncthreads();
  float tot = red[0] + red[1] + red[2] + red[3];
  float nrm = fmaxf(sqrtf(tot), 1e-12f);
  float q = v / nrm;
  pnN[p * 256 + c] = q;
  __hip_bfloat16 h = __float2bfloat16(q);
  pnBF[p * 256 + c] = *reinterpret_cast<ushort*>(&h);
}

// exact fp32 dot over 256 k for one (pos, proto); wave-collective tree reduce.
__device__ __forceinline__ float dot256(const float* __restrict__ xc,
                                        const float* __restrict__ pn, int l) {
  f32x4 pv = *reinterpret_cast<const f32x4*>(pn + (l << 2));
  float s = 0.f;
  #pragma unroll
  for (int j = 0; j < 4; ++j)
    s = fmaf(xc[(size_t)(((l << 2) + j)) << 10], pv[j], s);
  #pragma unroll
  for (int d = 1; d < 64; d <<= 1) s += __shfl_xor(s, d);
  return s;
}

// exact fp32 argmax over ALL 512 protos for one pos (rare 3-way path).
__device__ __forceinline__ int full512(const float* __restrict__ xc,
                                       const float* __restrict__ pnN, int l) {
  float a[8];
  #pragma unroll
  for (int pp = 0; pp < 8; ++pp) a[pp] = 0.f;
  #pragma unroll 1
  for (int k4 = 0; k4 < 64; ++k4) {
    float xv[4];
    #pragma unroll
    for (int j = 0; j < 4; ++j) xv[j] = xc[(size_t)(((k4 << 2) + j)) << 10];
    #pragma unroll
    for (int pp = 0; pp < 8; ++pp) {
      f32x4 pv = *reinterpret_cast<const f32x4*>(
          pnN + ((((l << 3) + pp)) << 8) + (k4 << 2));
      #pragma unroll
      for (int j = 0; j < 4; ++j) a[pp] = fmaf(xv[j], pv[j], a[pp]);
    }
  }
  float bs = NINF; int bp = 0;
  #pragma unroll
  for (int pp = 0; pp < 8; ++pp) {
    int p = (l << 3) + pp;
    if (a[pp] > bs) { bs = a[pp]; bp = p; }
  }
  #pragma unroll
  for (int d = 1; d < 64; d <<= 1) {
    float os = __shfl_xor(bs, d); int op = __shfl_xor(bp, d);
    bool take = (os > bs) || (os == bs && op < bp);
    bs = take ? os : bs; bp = take ? op : bp;
  }
  return bp;
}

// ---------------------------------------------------------------------------
// Kernel 2: r10 structure with the main loop INTERCHANGED (kk outer, pt
// inner unrolled). Per kk: B0/B1 built and consumed immediately (8 regs);
// acc[8][2] (64 regs, AGPR-eligible, non-rematerializable) accumulates.
// r9/r10's VGPR=60 showed B[2][8] was never kept resident -> per-pt
// rematerialization from L2 was the serial cost. Tail unchanged (validated).
// ---------------------------------------------------------------------------
__global__ __launch_bounds__(512, 2) void match_kernel(
    const float* __restrict__ x, const float* __restrict__ proto,
    const float* __restrict__ pnN, const ushort* __restrict__ pnBF,
    float* __restrict__ out) {
  __shared__ float m1s[2][4][32], m2s[2][4][32], m3s[2][4][32];
  __shared__ int   i1s[2][4][32], i2s[2][4][32];
  __shared__ int   idxl[64];

  const int t = threadIdx.x;
  const int l = t & 63, w = t >> 6;
  const int pg = w >> 2, wg = w & 3;
  const int lg = l >> 4, c16 = l & 15;
  const int n0 = blockIdx.x << 6;
  const int b = n0 >> 10, hw0 = n0 & 1023;
  const float* xg = x + ((size_t)b << 18) + hw0 + (pg << 5);

  // ---- main loop: kk outer, this wg's 8 proto-tiles inner ----
  f32x4 acc[8][2];
  #pragma unroll
  for (int pt = 0; pt < 8; ++pt) {
    acc[pt][0] = (f32x4){0.f, 0.f, 0.f, 0.f};
    acc[pt][1] = (f32x4){0.f, 0.f, 0.f, 0.f};
  }

  #pragma unroll 1
  for (int kk = 0; kk < 8; ++kk) {
    short8 B0, B1;
    #pragma unroll
    for (int j = 0; j < 8; ++j) {
      float f0 = xg[(size_t)(((kk << 5) + (lg << 3) + j)) << 10 |
                    (unsigned)(c16)];
      float f1 = xg[(size_t)(((kk << 5) + (lg << 3) + j)) << 10 |
                    (unsigned)(16 + c16)];
      __hip_bfloat16 h0 = __float2bfloat16(f0);
      __hip_bfloat16 h1 = __float2bfloat16(f1);
      B0[j] = *reinterpret_cast<short*>(&h0);
      B1[j] = *reinterpret_cast<short*>(&h1);
    }
    #pragma unroll
    for (int pt = 0; pt < 8; ++pt) {
      const short8 A = *reinterpret_cast<const short8*>(
          pnBF + (((((wg << 3) + pt) << 4) + c16) << 8) + (kk << 5) + (lg << 3));
      acc[pt][0] = __builtin_amdgcn_mfma_f32_16x16x32_bf16(A, B0, acc[pt][0], 0, 0, 0);
      acc[pt][1] = __builtin_amdgcn_mfma_f32_16x16x32_bf16(A, B1, acc[pt][1], 0, 0, 0);
    }
  }

  // ---- streaming top-3 extraction (same ascending-p order as r10) ----
  float m1[2] = {NINF, NINF}, m2[2] = {NINF, NINF}, m3[2] = {NINF, NINF};
  int i1[2] = {0, 0}, i2[2] = {0, 0};
  #pragma unroll
  for (int pt = 0; pt < 8; ++pt) {
    int pbase = ((((wg << 3) + pt)) << 4) + (lg << 2);
    #pragma unroll
    for (int r = 0; r < 4; ++r) {
      {
        float v = acc[pt][0][r]; int p = pbase + r;
        bool g1 = v > m1[0], g2 = v > m2[0], g3 = v > m3[0];
        m3[0] = g2 ? m2[0] : (g3 ? v : m3[0]);
        m2[0] = g1 ? m1[0] : (g2 ? v : m2[0]);
        i2[0] = g1 ? i1[0] : (g2 ? p : i2[0]);
        m1[0] = g1 ? v : m1[0];
        i1[0] = g1 ? p : i1[0];
      }
      {
        float v = acc[pt][1][r]; int p = pbase + r;
        bool g1 = v > m1[1], g2 = v > m2[1], g3 = v > m3[1];
        m3[1] = g2 ? m2[1] : (g3 ? v : m3[1]);
        m2[1] = g1 ? m1[1] : (g2 ? v : m2[1]);
        i2[1] = g1 ? i1[1] : (g2 ? p : i2[1]);
        m1[1] = g1 ? v : m1[1];
        i1[1] = g1 ? p : i1[1];
      }
    }
  }

  // ---- cross-lane merge within wave (validated) ----
  #pragma unroll
  for (int n = 0; n < 2; ++n) {
    #pragma unroll
    for (int d = 16; d <= 32; d <<= 1) {
      float bm1 = __shfl_xor(m1[n], d), bm2 = __shfl_xor(m2[n], d),
            bm3 = __shfl_xor(m3[n], d);
      int bi1 = __shfl_xor(i1[n], d), bi2 = __shfl_xor(i2[n], d);
      bool aF = (m1[n] > bm1) || (m1[n] == bm1 && i1[n] < bi1);
      float a1 = aF ? m1[n] : bm1, a2 = aF ? m2[n] : bm2, a3 = aF ? m3[n] : bm3;
      int ai1 = aF ? i1[n] : bi1, ai2 = aF ? i2[n] : bi2;
      float o1 = aF ? bm1 : m1[n], o2 = aF ? bm2 : m2[n];
      int oi1 = aF ? bi1 : i1[n];
      bool c2 = (a2 > o1) || (a2 == o1 && ai2 < oi1);
      m1[n] = a1; i1[n] = ai1;
      m2[n] = c2 ? a2 : o1; i2[n] = c2 ? ai2 : oi1;
      m3[n] = fmaxf(fmaxf(a3, o2), c2 ? o1 : a2);
    }
  }

  // ---- publish per-(pg,wg) top-3 tuples ----
  if (l < 32) {
    int n = l >> 4;
    m1s[pg][wg][l] = m1[n]; m2s[pg][wg][l] = m2[n]; m3s[pg][wg][l] = m3[n];
    i1s[pg][wg][l] = i1[n]; i2s[pg][wg][l] = i2[n];
  }
  __syncthreads();

  // ---- every wave merges its pg's 4 tuples (pos = l&31) ----
  int ap31 = l & 31;
  float M1 = m1s[pg][0][ap31], M2 = m2s[pg][0][ap31], M3 = m3s[pg][0][ap31];
  int I1 = i1s[pg][0][ap31], I2 = i2s[pg][0][ap31];
  #pragma unroll
  for (int q = 1; q < 4; ++q) {
    float o1 = m1s[pg][q][ap31], o2 = m2s[pg][q][ap31], o3 = m3s[pg][q][ap31];
    int oi1 = i1s[pg][q][ap31], oi2 = i2s[pg][q][ap31];
    bool aF = (M1 > o1) || (M1 == o1 && I1 < oi1);
    float a1 = aF ? M1 : o1, a2 = aF ? M2 : o2, a3 = aF ? M3 : o3;
    int ai1 = aF ? I1 : oi1, ai2 = aF ? I2 : oi2;
    float b1 = aF ? o1 : M1, b2 = aF ? o2 : M2;
    int bi1 = aF ? oi1 : I1;
    bool c2 = (a2 > b1) || (a2 == b1 && ai2 < bi1);
    M1 = a1; I1 = ai1;
    M2 = c2 ? a2 : b1; I2 = c2 ? ai2 : bi1;
    M3 = fmaxf(fmaxf(a3, b2), c2 ? b1 : a2);
  }

  bool need2 = (l < 32) && ((M1 - M2) < DELTA);
  bool need3 = (M1 - M3) < DELTA;
  unsigned long long bal = __ballot(need2);

  if (wg == 0 && l < 32 && !need2) idxl[(pg << 5) + l] = I1;

  unsigned long long msk = bal;
  int rank = 0;
  while (msk) {
    int ap = __ffsll(msk) - 1; msk &= msk - 1;
    if ((rank++ & 3) != wg) continue;
    int c1 = __shfl(I1, ap), cc2 = __shfl(I2, ap);
    int isC = __shfl((int)need3, ap);
    const float* xc = x + ((size_t)b << 18) + (hw0 + (pg << 5) + ap);
    int win;
    if (!isC) {
      float s1 = dot256(xc, pnN + (c1 << 8), l);
      float s2 = dot256(xc, pnN + (cc2 << 8), l);
      win = (s2 > s1 || (s2 == s1 && cc2 < c1)) ? cc2 : c1;
    } else {
      win = full512(xc, pnN, l);
    }
    if (l == 0) idxl[(pg << 5) + ap] = win;
  }
  __syncthreads();

  // ---- idx output ----
  if (t < 64) out[(size_t)NOUT + n0 + t] = (float)idxl[t];

  // ---- recon gather (validated): out[b][c][hw0+pos] = proto[idx][c] ----
  float* rb = out + ((size_t)b << 18) + hw0;
  #pragma unroll 1
  for (int it = 0; it < 32; ++it) {
    int lin = (it << 9) + t;
    int c = lin >> 6, pos = lin & 63;
    rb[((size_t)c << 10) + pos] = proto[(idxl[pos] << 8) + c];
  }
}

extern "C" void kernel_launch(void* const* d_in, const int* in_sizes, int n_in,
                              void* d_out, int out_size, void* d_ws, size_t ws_size,
                              hipStream_t stream) {
  const float* x = (const float*)d_in[0];        // (64, 256, 32, 32) f32
  const float* proto = (const float*)d_in[1];    // (512, 256) f32
  float* out = (float*)d_out;                    // 16777216 recon + 65536 idx
  float* pnN = (float*)d_ws;                     // 512*256 f32 = 512 KB
  ushort* pnBF = (ushort*)((char*)d_ws + 512 * 256 * sizeof(float)); // 256 KB

  proto_prep<<<512, 256, 0, stream>>>(proto, pnN, pnBF);
  match_kernel<<<1024, 512, 0, stream>>>(x, proto, pnN, pnBF, out);
}

// Round 12
// 139.845 us; speedup vs baseline: 3.4097x; 3.2172x over previous
//
#include <hip/hip_runtime.h>
#include <hip/hip_bf16.h>

typedef __attribute__((ext_vector_type(8))) short short8;
typedef __attribute__((ext_vector_type(4))) float f32x4;

#define NPOS  65536
#define NOUT  16777216
#define QCAP  240
#define DELTA 0.05f

// ---------------------------------------------------------------------------
// Kernel 1: normalize prototypes, write pnN f32 [p][k] and bf16 copy.
// ---------------------------------------------------------------------------
__global__ __launch_bounds__(256) void proto_prep(
    const float* __restrict__ proto, float* __restrict__ pnN,
    ushort* __restrict__ pnBF) {
  int p = blockIdx.x;       // 0..511
  int c = threadIdx.x;      // 0..255
  float v = proto[p * 256 + c];
  float s = v * v;
  #pragma unroll
  for (int off = 32; off > 0; off >>= 1) s += __shfl_down(s, off);
  __shared__ float red[4];
  int lane = c & 63, wid = c >> 6;
  if (lane == 0) red[wid] = s;
  __syncthreads();
  float tot = red[0] + red[1] + red[2] + red[3];
  float nrm = fmaxf(sqrtf(tot), 1e-12f);
  float q = v / nrm;
  pnN[p * 256 + c] = q;
  __hip_bfloat16 h = __float2bfloat16(q);
  pnBF[p * 256 + c] = *reinterpret_cast<ushort*>(&h);
}

// ---------------------------------------------------------------------------
// Kernel 2: r4's validated structure (119 us) with occupancy unlocked:
//  - raw shrunk 32->16 KB (4 staging phases), unioned with tail scratch
//    -> LDS 48.2 KB -> 3 blocks/CU (was 2 at 70 KB).
//  - __launch_bounds__(512,3): VGPR cap 85 >= r4's measured 64 (no spill).
//  - staging software-pipelined: phase p+1's float4 loads issued before
//    phase p's convert (8 extra VGPRs; HBM latency hidden under convert).
//  - GEMM/max/flag = r4 verbatim; resolve = r7's cnt-skip + packed atomicMax.
// ---------------------------------------------------------------------------
__global__ __launch_bounds__(512, 3) void match_kernel(
    const float* __restrict__ x, const float* __restrict__ proto,
    const float* __restrict__ pnN, const ushort* __restrict__ pnBF,
    float* __restrict__ out) {
  __shared__ __align__(16) ushort xbf[64 * 256];   // 32 KB bf16 [m][k] swizzled
  __shared__ __align__(16) union UU {
    float raw[64 * 64];                            // 16 KB f32 (quarter-K stage)
    struct {
      float wmax[8][64];
      float thr[64];
      int   queue[QCAP];
      unsigned long long b64[64];
      int   idxl[64];
      int   cnt[64];
      int   qn;
    } s;
  } u;

  const int t = threadIdx.x;
  const int l = t & 63, w = t >> 6;
  const int g = l >> 4, c16 = l & 15, r8 = l & 7;
  const int n0 = blockIdx.x << 6;
  const int b = n0 >> 10, hw0 = n0 & 1023;
  const float* xg = x + ((size_t)b << 18) + hw0;   // + k*1024 + pos

  // staging indices (constant per thread)
  const int kA = t >> 4;             // i=0 row (0..31)
  const int m4 = (t & 15) << 2;
  const int cm = t & 63, cR = t >> 6;   // convert: pos, 8-k chunk (0..7)

  // ---- software-pipelined staging: 4 phases x 64 k-rows ----
  float4 v0 = *reinterpret_cast<const float4*>(xg + ((size_t)kA << 10) + m4);
  float4 v1 = *reinterpret_cast<const float4*>(xg + ((size_t)(kA + 32) << 10) + m4);
  #pragma unroll 1
  for (int ph = 0; ph < 4; ++ph) {
    float4 nx0, nx1;
    if (ph < 3) {
      const float* s0 = xg + ((size_t)(((ph + 1) << 6) + kA) << 10) + m4;
      nx0 = *reinterpret_cast<const float4*>(s0);
      nx1 = *reinterpret_cast<const float4*>(s0 + (32 << 10));
    }
    *reinterpret_cast<float4*>(&u.raw[(kA << 6) + m4]) = v0;
    *reinterpret_cast<float4*>(&u.raw[((kA + 32) << 6) + m4]) = v1;
    __syncthreads();
    {
      short8 pk;
      #pragma unroll
      for (int j = 0; j < 8; ++j) {
        float f = u.raw[(((cR << 3) + j) << 6) + cm];
        __hip_bfloat16 h = __float2bfloat16(f);
        pk[j] = *reinterpret_cast<short*>(&h);
      }
      int chunk = (ph << 3) + cR;        // absolute 16B (8-k) chunk 0..31
      int dst = (cm << 8) + ((chunk ^ (cm & 7)) << 3);
      *reinterpret_cast<short8*>(&xbf[dst]) = pk;
    }
    __syncthreads();                     // raw reusable next phase
    v0 = nx0; v1 = nx1;
  }

  if (t == 0) u.s.qn = 0;
  if (t < 64) { u.s.cnt[t] = 0; u.s.b64[t] = 0ULL; }  // >=2 barriers pre-use

  // ---- bf16 GEMM (r4 verbatim): D[m][n], wave w owns protos w*64..+64 ----
  const ushort* pB0 = pnBF + (((w << 6) + c16) << 8) + (g << 3);
  f32x4 acc[4][4];
  #pragma unroll
  for (int mi = 0; mi < 4; ++mi)
    #pragma unroll
    for (int ni = 0; ni < 4; ++ni) acc[mi][ni] = (f32x4){0.f, 0.f, 0.f, 0.f};

  short8 Bcur[4], Bnxt[4];
  #pragma unroll
  for (int ni = 0; ni < 4; ++ni)
    Bcur[ni] = *reinterpret_cast<const short8*>(pB0 + (ni << 12));

  #pragma unroll
  for (int ks = 0; ks < 8; ++ks) {
    if (ks < 7) {
      #pragma unroll
      for (int ni = 0; ni < 4; ++ni)
        Bnxt[ni] = *reinterpret_cast<const short8*>(pB0 + (ni << 12) + ((ks + 1) << 5));
    }
    #pragma unroll
    for (int mi = 0; mi < 4; ++mi) {
      int chunk = (ks << 2) + g;
      const short8 a = *reinterpret_cast<const short8*>(
          &xbf[(((mi << 4) + c16) << 8) + ((chunk ^ r8) << 3)]);
      #pragma unroll
      for (int ni = 0; ni < 4; ++ni)
        acc[mi][ni] =
            __builtin_amdgcn_mfma_f32_16x16x32_bf16(a, Bcur[ni], acc[mi][ni], 0, 0, 0);
    }
    if (ks < 7) {
      #pragma unroll
      for (int ni = 0; ni < 4; ++ni) Bcur[ni] = Bnxt[ni];
    }
  }

  // ---- per-position block max (r4 verbatim) ----
  #pragma unroll
  for (int mi = 0; mi < 4; ++mi) {
    #pragma unroll
    for (int r = 0; r < 4; ++r) {
      float v = fmaxf(fmaxf(acc[mi][0][r], acc[mi][1][r]),
                      fmaxf(acc[mi][2][r], acc[mi][3][r]));
      #pragma unroll
      for (int s = 1; s < 16; s <<= 1) v = fmaxf(v, __shfl_xor(v, s));
      if (c16 == 0) u.s.wmax[w][(mi << 4) + (g << 2) + r] = v;
    }
  }
  __syncthreads();
  if (t < 64) {
    float bm = u.s.wmax[0][t];
    #pragma unroll
    for (int ww = 1; ww < 8; ++ww) bm = fmaxf(bm, u.s.wmax[ww][t]);
    u.s.thr[t] = bm - DELTA;
  }
  __syncthreads();

  // ---- flag candidates (r4 + cnt) ----
  #pragma unroll
  for (int mi = 0; mi < 4; ++mi)
    #pragma unroll
    for (int ni = 0; ni < 4; ++ni)
      #pragma unroll
      for (int r = 0; r < 4; ++r) {
        int pos = (mi << 4) + (g << 2) + r;
        if (acc[mi][ni][r] >= u.s.thr[pos]) {
          int slot = atomicAdd(&u.s.qn, 1);
          atomicAdd(&u.s.cnt[pos], 1);
          if (slot < QCAP)
            u.s.queue[slot] = (((w << 6) + (ni << 4) + c16) << 6) | pos;
        }
      }
  __syncthreads();

  // ---- resolve: cnt==1 direct; cnt>1 exact fp32 rescore + packed atomicMax -
  int n = u.s.qn < QCAP ? u.s.qn : QCAP;
  for (int j = t; j < n; j += 512) {
    int e = u.s.queue[j];
    int pos = e & 63, p = e >> 6;
    if (u.s.cnt[pos] == 1) {
      u.s.idxl[pos] = p;               // sole candidate == argmax
    } else {
      float a = 0.f;                   // exact sequential fmaf (validated)
      const float* pr = pnN + (p << 8);
      for (int k = 0; k < 256; ++k)
        a = fmaf(xg[(k << 10) + pos], pr[k], a);
      unsigned int ub = __float_as_uint(a);
      ub ^= (unsigned int)(((int)ub >> 31)) | 0x80000000u;  // orderable
      unsigned long long key =
          ((unsigned long long)ub << 32) | (unsigned long long)(511 - p);
      atomicMax(&u.s.b64[pos], key);   // ties: larger (511-p) => smaller p
    }
  }
  __syncthreads();

  // ---- write indices ----
  if (t < 64) {
    int bp = (u.s.cnt[t] == 1) ? u.s.idxl[t]
                               : 511 - (int)(u.s.b64[t] & 511ULL);
    u.s.idxl[t] = bp;
    out[(size_t)NOUT + n0 + t] = (float)bp;
  }
  __syncthreads();

  // ---- recon gather: out[b][c][hw0+pos] = proto[idx[pos]][c] ----
  float* rb = out + ((size_t)b << 18) + hw0;
  #pragma unroll 1
  for (int it = 0; it < 32; ++it) {
    int lin = (it << 9) + t;
    int c = lin >> 6, pos = lin & 63;
    rb[((size_t)c << 10) + pos] = proto[(u.s.idxl[pos] << 8) + c];
  }
}

extern "C" void kernel_launch(void* const* d_in, const int* in_sizes, int n_in,
                              void* d_out, int out_size, void* d_ws, size_t ws_size,
                              hipStream_t stream) {
  const float* x = (const float*)d_in[0];        // (64, 256, 32, 32) f32
  const float* proto = (const float*)d_in[1];    // (512, 256) f32
  float* out = (float*)d_out;                    // 16777216 recon + 65536 idx
  float* pnN = (float*)d_ws;                     // 512*256 f32 = 512 KB
  ushort* pnBF = (ushort*)((char*)d_ws + 512 * 256 * sizeof(float)); // 256 KB

  proto_prep<<<512, 256, 0, stream>>>(proto, pnN, pnBF);
  match_kernel<<<NPOS / 64, 512, 0, stream>>>(x, proto, pnN, pnBF, out);
}